// Round 13
// baseline (964.349 us; speedup 1.0000x reference)
//
#include <hip/hip_runtime.h>
#include <cmath>

// ---------------------------------------------------------------------------
// FDFD Ez solve, adjoint + symmetrized, pipelined COCG:
//   out[b,o] = sigmoid(-(c0*|s_b^T z_o| - E0[o])*alpha),  A^T z_o = p_o
// D = diag(sqrt(sxf)*sqrt(syf)):  B = D A D^-1 complex-symmetric,
//   A^T z = p  <=>  B y = D^-1 p,  z = D y.
// COCG, ONE fused 12-float reduction/iter; x never stored (functional
// qacc += alpha*(D ics_i, p)u redundantly per-thread).
// Round 13 (per-iter surgery at proven MAXIT=144):
//  * bar3 eliminated CORRECTLY (round-10 failed with 96 serial ds_reads/thread):
//    after bar2, ALL waves do a lane-distributed cross-wave sum -- lane l reads
//    1-2 floats of s_part, 3 shfl_xor levels sum over waves, 12 shfl
//    broadcasts. 2 barriers/iter, no wave-0 serialization, no s_scal4/s_flag.
//  * fixed trip count; reduction 13 -> 12 floats (drop ||r||^2 conv test).
// ---------------------------------------------------------------------------

namespace {
constexpr int NXg   = 128;
constexpr int NYg   = 52;
constexpr int Ng    = NXg * NYg;      // 6656
constexpr int NPMLg = 10;
constexpr int NT    = 512;            // 8 waves
constexpr int CPT   = 13;             // 512*13 = 6656 exactly
constexpr int NW    = NT / 64;        // 8
constexpr int NZMAX = 1280;           // pads LDS >80KB -> 1 block/CU
constexpr int MAXIT = 144;
constexpr int WAVG  = 32;             // tail-averaging window for functional

constexpr double D_PI    = 3.14159265358979323846;
constexpr double D_DL    = 2.5e-8;
constexpr double D_EPS0  = 8.85418782e-12;
constexpr double D_MU0   = 4e-7 * D_PI;
constexpr double D_OMEGA = 2.0 * D_PI * 2e14;
}

// ---- double complex helpers (init only) -----------------------------------
struct dcx { double x, y; };
__device__ __forceinline__ dcx dmul(dcx a, dcx b) {
    return {a.x * b.x - a.y * b.y, a.x * b.y + a.y * b.x};
}
__device__ __forceinline__ dcx dadd(dcx a, dcx b) { return {a.x + b.x, a.y + b.y}; }
__device__ __forceinline__ dcx drec(dcx a) {
    double d = a.x * a.x + a.y * a.y;
    return {a.x / d, -a.y / d};
}
__device__ __forceinline__ dcx dsqr(dcx a) {   // principal sqrt
    double r = sqrt(a.x * a.x + a.y * a.y);
    double re = sqrt(0.5 * (r + a.x));
    double im = sqrt(0.5 * fmax(r - a.x, 0.0));
    if (a.y < 0.0) im = -im;
    return {re, im};
}
__device__ __forceinline__ float2 tof2(dcx a) { return make_float2((float)a.x, (float)a.y); }

// ---- float complex helpers ------------------------------------------------
__device__ __forceinline__ float2 cmulf(float2 a, float2 b) {
    return make_float2(a.x * b.x - a.y * b.y, a.x * b.y + a.y * b.x);
}
__device__ __forceinline__ float2 caddf(float2 a, float2 b) {
    return make_float2(a.x + b.x, a.y + b.y);
}
__device__ __forceinline__ float2 csubf(float2 a, float2 b) {
    return make_float2(a.x - b.x, a.y - b.y);
}
__device__ __forceinline__ float2 cdivf(float2 a, float2 b) {
    float d = b.x * b.x + b.y * b.y;
    return make_float2((a.x * b.x + a.y * b.y) / d, (a.y * b.x - a.x * b.y) / d);
}

// SC-PML stretch factor s = 1 - i*sigma/(omega*eps0)
__device__ inline dcx sfac(int n, double pos) {
    double dlo = fmax((double)NPMLg - pos, 0.0);
    double dhi = fmax(pos - (double)(n - 1 - NPMLg), 0.0);
    double dpml = NPMLg * D_DL;
    double d = fmax(dlo, dhi) * D_DL;
    double eta0 = sqrt(D_MU0 / D_EPS0);
    double smax = -4.0 * log(1e-8) / (2.0 * eta0 * dpml);
    double t = d / dpml;
    double sigma = smax * t * t * t;
    return dcx{1.0, -sigma / (D_OMEGA * D_EPS0)};
}

__global__ void __launch_bounds__(NT, 2)
fdfd_cocg13(const float* __restrict__ masks, const float* __restrict__ rho_in,
            const float* __restrict__ E0s, const float* __restrict__ alpha_in,
            const float* __restrict__ ics, const float* __restrict__ probes,
            const float* __restrict__ bg_rho, const float* __restrict__ opt_region,
            float* __restrict__ out) {
    const int tid  = threadIdx.x;
    const int lane = tid & 63;
    const int wid  = tid >> 6;
    const int o    = blockIdx.x;   // probe index

    __shared__ float2 s_p[Ng];                         // 53248 B
    __shared__ float  s_part[NW][16];                  // 512 B (12 used)
    __shared__ int    s_cnt;
    __shared__ float2 s_gx[NXg], s_cxs[NXg], s_rx[NXg];
    __shared__ float2 s_gy[NYg], s_cys[NYg], s_ry[NYg];
    __shared__ int    s_nzi[NZMAX];                    // nonzero-source cells
    __shared__ float4 s_nzw[NZMAX];                    // (ics0*D, ics1*D)

    if (tid == 0) s_cnt = 0;

    // ---- 1-D coefficient arrays (double precision init) ------------------
    if (tid < NXg) {
        int ix = tid;
        int ixp = (ix + 1 < NXg) ? ix + 1 : 0;
        dcx f0 = sfac(NXg, (double)ix + 0.5);
        dcx f1 = sfac(NXg, (double)ixp + 0.5);
        dcx b0 = sfac(NXg, (double)ix);
        dcx b1 = sfac(NXg, (double)ixp);
        dcx cxp = drec(dmul(f0, b1));
        dcx cxm = drec(dmul(f0, b0));
        s_cxs[ix] = tof2(dadd(cxp, cxm));
        s_gx[ix]  = tof2(drec(dmul(b1, dmul(dsqr(f0), dsqr(f1)))));
        s_rx[ix]  = tof2(dsqr(f0));
    } else if (tid < NXg + NYg) {
        int iy = tid - NXg;
        int iyp = (iy + 1 < NYg) ? iy + 1 : 0;
        dcx f0 = sfac(NYg, (double)iy + 0.5);
        dcx f1 = sfac(NYg, (double)iyp + 0.5);
        dcx b0 = sfac(NYg, (double)iy);
        dcx b1 = sfac(NYg, (double)iyp);
        dcx cyp = drec(dmul(f0, b1));
        dcx cym = drec(dmul(f0, b0));
        s_cys[iy] = tof2(dadd(cyp, cym));
        s_gy[iy]  = tof2(drec(dmul(b1, dmul(dsqr(f0), dsqr(f1)))));
        s_ry[iy]  = tof2(dsqr(f0));
    }
    __syncthreads();

    // ---- per-cell init ----------------------------------------------------
    const float k2 = (float)((D_OMEGA * D_DL) * (D_OMEGA * D_DL) * D_MU0 * D_EPS0);
    float2 pown[CPT], rv[CPT], dg[CPT];
    #pragma unroll
    for (int k = 0; k < CPT; ++k) {
        int c = tid + NT * k;
        int ix = c / NYg;
        int iy = c - ix * NYg;
        float rt = opt_region[c] * rho_in[c] + (1.f - opt_region[c]) * bg_rho[c];
        rt = fminf(fmaxf(rt, 0.f), 1.f);
        float epsr = 1.f + 11.f * rt;
        float2 d2 = caddf(s_cxs[ix], s_cys[iy]);
        dg[k] = make_float2(-d2.x + k2 * epsr, -d2.y);
        float2 dd = cmulf(s_rx[ix], s_ry[iy]);         // D_ii
        float pb = probes[o * Ng + c];
        float2 r0 = cdivf(make_float2(pb, 0.f), dd);   // rhs = D^-1 p
        rv[k] = r0;
        pown[k] = r0;
        s_p[c] = r0;
        float i0 = ics[c];
        float i1 = ics[Ng + c];
        if (i0 != 0.f || i1 != 0.f) {
            int idx = atomicAdd(&s_cnt, 1);
            if (idx < NZMAX) {
                s_nzi[idx] = c;
                s_nzw[idx] = make_float4(i0 * dd.x, i0 * dd.y, i1 * dd.x, i1 * dd.y);
            }
        }
    }
    __syncthreads();
    const int cnt = min(s_cnt, NZMAX);

    float2 qacc0 = make_float2(0.f, 0.f);   // redundant per-thread copies
    float2 qacc1 = make_float2(0.f, 0.f);
    float2 qsum0 = make_float2(0.f, 0.f);   // tail-average accumulators
    float2 qsum1 = make_float2(0.f, 0.f);

    // ---- COCG main loop (fixed trip count, 2 barriers/iter) ----------------
    for (int it = 0; it < MAXIT; ++it) {
        __syncthreads();                               // bar1: prev s_p writes visible
        float2 qv[CPT];
        float prt[12];
        #pragma unroll
        for (int j = 0; j < 12; ++j) prt[j] = 0.f;

        #pragma unroll
        for (int k = 0; k < CPT; ++k) {
            int c = tid + NT * k;
            int ix = c / NYg;
            int iy = c - ix * NYg;
            int ixm = (ix > 0) ? ix - 1 : NXg - 1;
            int iym = (iy > 0) ? iy - 1 : NYg - 1;
            int cxp = (ix + 1 < NXg) ? c + NYg : c - (NXg - 1) * NYg;
            int cxm = (ix > 0) ? c - NYg : c + (NXg - 1) * NYg;
            int cyp = (iy + 1 < NYg) ? c + 1 : c - (NYg - 1);
            int cym = (iy > 0) ? c - 1 : c + (NYg - 1);
            float2 q = cmulf(dg[k], pown[k]);
            q = caddf(q, cmulf(s_gx[ix],  s_p[cxp]));
            q = caddf(q, cmulf(s_gx[ixm], s_p[cxm]));
            q = caddf(q, cmulf(s_gy[iy],  s_p[cyp]));
            q = caddf(q, cmulf(s_gy[iym], s_p[cym]));
            qv[k] = q;
            float2 p = pown[k], r = rv[k];
            prt[0]  += p.x * q.x - p.y * q.y;     // (p,q)u
            prt[1]  += p.x * q.y + p.y * q.x;
            prt[2]  += r.x * r.x - r.y * r.y;     // (r,r)u  (exact rho_t)
            prt[3]  += 2.f * r.x * r.y;
            prt[4]  += r.x * q.x - r.y * q.y;     // (r,q)u
            prt[5]  += r.x * q.y + r.y * q.x;
            prt[6]  += q.x * q.x - q.y * q.y;     // (q,q)u
            prt[7]  += 2.f * q.x * q.y;
        }
        if (tid < cnt) {                          // sparse source projections
            float2 pc = s_p[s_nzi[tid]];
            float4 w4 = s_nzw[tid];
            prt[8]  += w4.x * pc.x - w4.y * pc.y;   // (D ics0, p)u
            prt[9]  += w4.x * pc.y + w4.y * pc.x;
            prt[10] += w4.z * pc.x - w4.w * pc.y;   // (D ics1, p)u
            prt[11] += w4.z * pc.y + w4.w * pc.x;
        }
        #pragma unroll
        for (int s = 32; s > 0; s >>= 1) {
            #pragma unroll
            for (int j = 0; j < 12; ++j) prt[j] += __shfl_xor(prt[j], s);
        }
        if (lane == 0) {
            #pragma unroll
            for (int j = 0; j < 12; ++j) s_part[wid][j] = prt[j];
        }
        __syncthreads();                               // bar2: partials visible, s_p reads done

        // lane-distributed cross-wave sum (ALL waves, redundant):
        // lane l reads s_part[l&7][l>>3] (j=0..7) and, for l<32, s_part[l&7][8+(l>>3)]
        int w8 = lane & 7, j8 = lane >> 3;
        float va = s_part[w8][j8];
        float vb = (lane < 32) ? s_part[w8][8 + j8] : 0.f;
        va += __shfl_xor(va, 1); va += __shfl_xor(va, 2); va += __shfl_xor(va, 4);
        vb += __shfl_xor(vb, 1); vb += __shfl_xor(vb, 2); vb += __shfl_xor(vb, 4);
        float red[12];
        #pragma unroll
        for (int j = 0; j < 8; ++j) red[j] = __shfl(va, j * 8);
        #pragma unroll
        for (int j = 0; j < 4; ++j) red[8 + j] = __shfl(vb, j * 8);

        float2 pq  = make_float2(red[0], red[1]);
        float2 rho = make_float2(red[2], red[3]);
        float2 rqu = make_float2(red[4], red[5]);
        float2 qqu = make_float2(red[6], red[7]);
        float2 al  = cdivf(rho, pq);
        float2 rho_n = csubf(rho, cmulf(make_float2(2.f * al.x, 2.f * al.y), rqu));
        rho_n = caddf(rho_n, cmulf(cmulf(al, al), qqu));
        float2 be = cdivf(rho_n, rho);
        qacc0 = caddf(qacc0, cmulf(al, make_float2(red[8],  red[9])));
        qacc1 = caddf(qacc1, cmulf(al, make_float2(red[10], red[11])));
        if (it >= MAXIT - WAVG) {                      // tail-average window
            qsum0 = caddf(qsum0, qacc0);
            qsum1 = caddf(qsum1, qacc1);
        }
        #pragma unroll
        for (int k = 0; k < CPT; ++k) {
            rv[k] = csubf(rv[k], cmulf(al, qv[k]));
            float2 pn = caddf(rv[k], cmulf(be, pown[k]));
            pown[k] = pn;
            s_p[tid + NT * k] = pn;                    // safe: all reads done at bar2
        }
    }

    // ---- epilogue (every thread holds identical tail-averaged functional) --
    if (tid == 0) {
        const float inv = 1.f / (float)WAVG;
        float2 q0 = make_float2(qsum0.x * inv, qsum0.y * inv);
        float2 q1 = make_float2(qsum1.x * inv, qsum1.y * inv);
        const float c0 = (float)(D_OMEGA * D_MU0 * D_DL * D_DL);
        float E0 = E0s[o];
        float al = alpha_in[0];
        #pragma unroll
        for (int b = 0; b < 8; ++b) {
            float m0 = masks[2 * b], m1 = masks[2 * b + 1];
            float re = m0 * q0.x + m1 * q1.x;
            float im = m0 * q0.y + m1 * q1.y;
            float ov = c0 * sqrtf(re * re + im * im);
            out[2 * b + o] = 1.f / (1.f + expf((ov - E0) * al));
        }
    }
}

extern "C" void kernel_launch(void* const* d_in, const int* in_sizes, int n_in,
                              void* d_out, int out_size, void* d_ws, size_t ws_size,
                              hipStream_t stream) {
    (void)in_sizes; (void)n_in; (void)d_ws; (void)ws_size; (void)out_size;
    fdfd_cocg13<<<dim3(2), dim3(NT), 0, stream>>>(
        (const float*)d_in[0],   // masks      (8,2)
        (const float*)d_in[1],   // rho        (128,52)
        (const float*)d_in[2],   // E0s        (2,)
        (const float*)d_in[3],   // alpha      (1,)
        (const float*)d_in[4],   // ics        (2,128,52)
        (const float*)d_in[5],   // probes     (2,128,52)
        (const float*)d_in[6],   // bg_rho     (128,52)
        (const float*)d_in[7],   // opt_region (128,52)
        (float*)d_out);          // (8,2) float32
}